// Round 5
// baseline (971.062 us; speedup 1.0000x reference)
//
#include <hip/hip_runtime.h>

#define N_NODES 100000
#define N_EDGES 1600000
#define NPB 32                       // nodes per bucket (dst >> 5)
#define NB (N_NODES / NPB)           // 3125 buckets (exact: 3125*32 = 100000)
#define CAP 704                      // slots per bucket (mean 512 + 8.5 sigma)

// ---------------- JAX threefry2x32 (partitionable scheme) ----------------
struct U2 { unsigned a, b; };

__host__ __device__ constexpr U2 tf2x32(unsigned k0, unsigned k1, unsigned c0, unsigned c1) {
  unsigned ks2 = k0 ^ k1 ^ 0x1BD11BDAu;
  unsigned x0 = c0 + k0, x1 = c1 + k1;
#define TFR(r) { x0 += x1; x1 = (x1 << (r)) | (x1 >> (32 - (r))); x1 ^= x0; }
  TFR(13) TFR(15) TFR(26) TFR(6)
  x0 += k1;  x1 += ks2 + 1u;
  TFR(17) TFR(29) TFR(16) TFR(24)
  x0 += ks2; x1 += k0 + 2u;
  TFR(13) TFR(15) TFR(26) TFR(6)
  x0 += k0;  x1 += k1 + 3u;
  TFR(17) TFR(29) TFR(16) TFR(24)
  x0 += k1;  x1 += ks2 + 4u;
  TFR(13) TFR(15) TFR(26) TFR(6)
  x0 += ks2; x1 += k0 + 5u;
#undef TFR
  return U2{x0, x1};
}

constexpr U2 DK0 = tf2x32(0u, 42u, 0u, 0u);
constexpr U2 DK1 = tf2x32(0u, 42u, 0u, 1u);

__device__ __forceinline__ bool keep_bit(unsigned k0, unsigned k1, unsigned j) {
  U2 w = tf2x32(k0, k1, 0u, j);
  return ((w.a ^ w.b) >> 31) == 0u;
}

// ---------------- Kernel A: xl = x@W1_l, xr = x@W1_r (wave per row) -------
__global__ __launch_bounds__(256) void k_transform1(
    const float* __restrict__ x, const float* __restrict__ Wl,
    const float* __restrict__ Wr, float* __restrict__ xl,
    float* __restrict__ xr) {
  int wid = (int)((blockIdx.x * blockDim.x + threadIdx.x) >> 6);
  int lane = threadIdx.x & 63;
  if (wid >= N_NODES) return;
  float xv = x[wid * 64 + lane];
  const float* W = (lane < 32) ? Wl : Wr;
  int c = lane & 31;
  float s = 0.f;
#pragma unroll
  for (int k = 0; k < 64; ++k) {
    float b = __shfl(xv, k, 64);
    s += b * W[k * 32 + c];
  }
  if (lane < 32) xl[wid * 32 + c] = s;
  else           xr[wid * 32 + c] = s;
}

// ---------------- Binning: append packed (src | dstLocal<<17) -------------
// Only NB=3125 write frontiers -> frontier lines stay L2-resident and
// consecutive appends merge into full sectors (vs per-node scatter's 64B/edge).
__global__ __launch_bounds__(256) void k_bin(
    const int* __restrict__ src, const int* __restrict__ dst,
    int* __restrict__ cur, unsigned* __restrict__ buf) {
  int e = (int)(blockIdx.x * blockDim.x + threadIdx.x);
  if (e >= N_EDGES) return;
  int d = dst[e];
  int b = d >> 5;
  unsigned packed = (unsigned)src[e] | ((unsigned)(d & 31) << 17);
  int p = atomicAdd(&cur[b], 1);
  if (p < CAP) buf[(size_t)b * CAP + p] = packed;
}

// ---- Layer 1: block per bucket; LDS-accumulate mean(xl[nbrs]); epilogue --
__global__ __launch_bounds__(256) void k_agg1(
    const unsigned* __restrict__ buf, const int* __restrict__ cur,
    const float* __restrict__ xl, const float* __restrict__ xr,
    const float* __restrict__ b1, float* __restrict__ hp) {
  __shared__ float acc[NPB * 32];
  __shared__ float cnt[NPB];
  int b = blockIdx.x;
  int t = threadIdx.x;
  for (int i = t; i < NPB * 32; i += 256) acc[i] = 0.f;
  if (t < NPB) cnt[t] = 0.f;
  __syncthreads();
  int nb = min(cur[b], CAP);
  const unsigned* eb = buf + (size_t)b * CAP;
  int c = t & 31, hw = t >> 5;                 // 8 half-waves per block
  int j = hw;
  for (; j + 24 < nb; j += 32) {               // 4 edges in flight per half
    unsigned w0 = eb[j], w1 = eb[j + 8], w2 = eb[j + 16], w3 = eb[j + 24];
    int s0 = w0 & 0x1FFFF, d0 = w0 >> 17;
    int s1 = w1 & 0x1FFFF, d1 = w1 >> 17;
    int s2 = w2 & 0x1FFFF, d2 = w2 >> 17;
    int s3 = w3 & 0x1FFFF, d3 = w3 >> 17;
    float a0 = xl[s0 * 32 + c];
    float a1 = xl[s1 * 32 + c];
    float a2 = xl[s2 * 32 + c];
    float a3 = xl[s3 * 32 + c];
    atomicAdd(&acc[d0 * 32 + c], a0);
    atomicAdd(&acc[d1 * 32 + c], a1);
    atomicAdd(&acc[d2 * 32 + c], a2);
    atomicAdd(&acc[d3 * 32 + c], a3);
    if (c == 0) {
      atomicAdd(&cnt[d0], 1.f); atomicAdd(&cnt[d1], 1.f);
      atomicAdd(&cnt[d2], 1.f); atomicAdd(&cnt[d3], 1.f);
    }
  }
  for (; j < nb; j += 8) {
    unsigned w = eb[j];
    int s = w & 0x1FFFF, dl = w >> 17;
    atomicAdd(&acc[dl * 32 + c], xl[s * 32 + c]);
    if (c == 0) atomicAdd(&cnt[dl], 1.f);
  }
  __syncthreads();
  // epilogue: mean + b1 + xr, leaky_relu, dropout (mask DK0)
  for (int e = t; e < NPB * 32; e += 256) {
    int dl = e >> 5, cc = e & 31;
    int g = b * (NPB * 32) + e;                // == node*32 + cc
    float inv = 1.0f / fmaxf(cnt[dl], 1.0f);
    float v = acc[e] * inv + b1[cc] + xr[g];
    v = (v > 0.f) ? v : 0.01f * v;
    hp[g] = keep_bit(DK0.a, DK0.b, (unsigned)g) ? 2.0f * v : 0.0f;
  }
}

// ---- Layer 2: LDS-accumulate mean(hp[nbrs]); GEMM+dropout+L2norm epilogue -
__global__ __launch_bounds__(256) void k_agg2(
    const unsigned* __restrict__ buf, const int* __restrict__ cur,
    const float* __restrict__ hp, const float* __restrict__ W2l,
    const float* __restrict__ b2, const float* __restrict__ W2r,
    float* __restrict__ out) {
  __shared__ float acc[NPB * 32];
  __shared__ float cnt[NPB];
  int b = blockIdx.x;
  int t = threadIdx.x;
  for (int i = t; i < NPB * 32; i += 256) acc[i] = 0.f;
  if (t < NPB) cnt[t] = 0.f;
  __syncthreads();
  int nb = min(cur[b], CAP);
  const unsigned* eb = buf + (size_t)b * CAP;
  int c = t & 31, hw = t >> 5;
  int j = hw;
  for (; j + 24 < nb; j += 32) {
    unsigned w0 = eb[j], w1 = eb[j + 8], w2 = eb[j + 16], w3 = eb[j + 24];
    int s0 = w0 & 0x1FFFF, d0 = w0 >> 17;
    int s1 = w1 & 0x1FFFF, d1 = w1 >> 17;
    int s2 = w2 & 0x1FFFF, d2 = w2 >> 17;
    int s3 = w3 & 0x1FFFF, d3 = w3 >> 17;
    float a0 = hp[s0 * 32 + c];
    float a1 = hp[s1 * 32 + c];
    float a2 = hp[s2 * 32 + c];
    float a3 = hp[s3 * 32 + c];
    atomicAdd(&acc[d0 * 32 + c], a0);
    atomicAdd(&acc[d1 * 32 + c], a1);
    atomicAdd(&acc[d2 * 32 + c], a2);
    atomicAdd(&acc[d3 * 32 + c], a3);
    if (c == 0) {
      atomicAdd(&cnt[d0], 1.f); atomicAdd(&cnt[d1], 1.f);
      atomicAdd(&cnt[d2], 1.f); atomicAdd(&cnt[d3], 1.f);
    }
  }
  for (; j < nb; j += 8) {
    unsigned w = eb[j];
    int s = w & 0x1FFFF, dl = w >> 17;
    atomicAdd(&acc[dl * 32 + c], hp[s * 32 + c]);
    if (c == 0) atomicAdd(&cnt[dl], 1.f);
  }
  __syncthreads();
  // epilogue: wave per node (4 waves x 8 nodes)
  int lane = t & 63, wv = t >> 6;
#pragma unroll
  for (int i = 0; i < NPB / 4; ++i) {
    int n = wv + 4 * i;
    int g = b * NPB + n;
    float inv = 1.0f / fmaxf(cnt[n], 1.0f);
    // lanes 0..31: aggregated mean row; lanes 32..63: node's own hp row
    float rv = (lane < 32) ? acc[n * 32 + lane] * inv
                           : hp[g * 32 + (lane - 32)];
    float s1 = 0.f, s2 = 0.f;
#pragma unroll
    for (int kk = 0; kk < 32; ++kk) {
      float a = __shfl(rv, kk, 64);
      float h = __shfl(rv, 32 + kk, 64);
      s1 += a * W2l[kk * 64 + lane];
      s2 += h * W2r[kk * 64 + lane];
    }
    float v = s1 + b2[lane] + s2;
    unsigned jj = (unsigned)(g * 64 + lane);
    float d = keep_bit(DK1.a, DK1.b, jj) ? 2.0f * v : 0.0f;
    float ss = d * d;
#pragma unroll
    for (int o = 32; o > 0; o >>= 1) ss += __shfl_xor(ss, o, 64);
    float scale = 1.0f / fmaxf(sqrtf(ss), 1e-12f);
    out[jj] = d * scale;
  }
}

// --------------------------------------------------------------------------
extern "C" void kernel_launch(void* const* d_in, const int* in_sizes, int n_in,
                              void* d_out, int out_size, void* d_ws, size_t ws_size,
                              hipStream_t stream) {
  const float* x   = (const float*)d_in[0];
  const int*   ei  = (const int*)d_in[1];
  const float* W1l = (const float*)d_in[2];
  const float* b1  = (const float*)d_in[3];
  const float* W1r = (const float*)d_in[4];
  const float* W2l = (const float*)d_in[5];
  const float* b2  = (const float*)d_in[6];
  const float* W2r = (const float*)d_in[7];
  float* out = (float*)d_out;

  const int* src = ei;            // edge_index[0]
  const int* dst = ei + N_EDGES;  // edge_index[1]

  const size_t F32 = (size_t)N_NODES * 32;
  float* xl      = (float*)d_ws;                 // 12.8 MB
  float* xr      = xl + F32;                     // 12.8 MB
  float* hp      = xr + F32;                     // 12.8 MB
  int* cur       = (int*)(hp + F32);             // 12.5 KB
  unsigned* buf  = (unsigned*)(cur + NB);        // 3125*704*4 = 8.8 MB

  hipMemsetAsync(cur, 0, (size_t)NB * sizeof(int), stream);

  const int EB = (N_EDGES + 255) / 256;
  k_bin<<<EB, 256, 0, stream>>>(src, dst, cur, buf);
  k_transform1<<<(N_NODES + 3) / 4, 256, 0, stream>>>(x, W1l, W1r, xl, xr);
  k_agg1<<<NB, 256, 0, stream>>>(buf, cur, xl, xr, b1, hp);
  k_agg2<<<NB, 256, 0, stream>>>(buf, cur, hp, W2l, b2, W2r, out);
}

// Round 6
// 385.872 us; speedup vs baseline: 2.5165x; 2.5165x over previous
//
#include <hip/hip_runtime.h>

#define N_NODES 100000
#define N_EDGES 1600000
#define NPB 32                       // nodes per bucket (dst >> 5)
#define NB (N_NODES / NPB)           // 3125 buckets
#define SEG 8                        // segments per bucket (XCD-local append)
#define CAP_S 128                    // slots per segment (mean 64 + 8 sigma)

// ---------------- JAX threefry2x32 (partitionable scheme) ----------------
struct U2 { unsigned a, b; };

__host__ __device__ constexpr U2 tf2x32(unsigned k0, unsigned k1, unsigned c0, unsigned c1) {
  unsigned ks2 = k0 ^ k1 ^ 0x1BD11BDAu;
  unsigned x0 = c0 + k0, x1 = c1 + k1;
#define TFR(r) { x0 += x1; x1 = (x1 << (r)) | (x1 >> (32 - (r))); x1 ^= x0; }
  TFR(13) TFR(15) TFR(26) TFR(6)
  x0 += k1;  x1 += ks2 + 1u;
  TFR(17) TFR(29) TFR(16) TFR(24)
  x0 += ks2; x1 += k0 + 2u;
  TFR(13) TFR(15) TFR(26) TFR(6)
  x0 += k0;  x1 += k1 + 3u;
  TFR(17) TFR(29) TFR(16) TFR(24)
  x0 += k1;  x1 += ks2 + 4u;
  TFR(13) TFR(15) TFR(26) TFR(6)
  x0 += ks2; x1 += k0 + 5u;
#undef TFR
  return U2{x0, x1};
}

constexpr U2 DK0 = tf2x32(0u, 42u, 0u, 0u);
constexpr U2 DK1 = tf2x32(0u, 42u, 0u, 1u);

__device__ __forceinline__ bool keep_bit(unsigned k0, unsigned k1, unsigned j) {
  U2 w = tf2x32(k0, k1, 0u, j);
  return ((w.a ^ w.b) >> 31) == 0u;
}

// ---------------- Kernel A: xl = x@W1_l, xr = x@W1_r (wave per row) -------
__global__ __launch_bounds__(256) void k_transform1(
    const float* __restrict__ x, const float* __restrict__ Wl,
    const float* __restrict__ Wr, float* __restrict__ xl,
    float* __restrict__ xr) {
  int wid = (int)((blockIdx.x * blockDim.x + threadIdx.x) >> 6);
  int lane = threadIdx.x & 63;
  if (wid >= N_NODES) return;
  float xv = x[wid * 64 + lane];
  const float* W = (lane < 32) ? Wl : Wr;
  int c = lane & 31;
  float s = 0.f;
#pragma unroll
  for (int k = 0; k < 64; ++k) {
    float b = __shfl(xv, k, 64);
    s += b * W[k * 32 + c];
  }
  if (lane < 32) xl[wid * 32 + c] = s;
  else           xr[wid * 32 + c] = s;
}

// ---------------- Binning: 8 XCD-local segments per bucket ---------------
// seg = blockIdx & 7 tracks the round-robin workgroup->XCD mapping, so each
// segment's write frontier stays in one XCD's L2 and appends merge into
// full sectors (k_fill's per-node scatter paid 64B of HBM per 4B store).
__global__ __launch_bounds__(256) void k_bin(
    const int* __restrict__ src, const int* __restrict__ dst,
    int* __restrict__ scur, unsigned* __restrict__ buf) {
  int e = (int)(blockIdx.x * blockDim.x + threadIdx.x);
  if (e >= N_EDGES) return;
  int d = dst[e];
  int cell = (d >> 5) * SEG + (blockIdx.x & (SEG - 1));
  unsigned packed = (unsigned)src[e] | ((unsigned)(d & 31) << 17);
  int p = atomicAdd(&scur[cell], 1);
  if (p < CAP_S) buf[(size_t)cell * CAP_S + p] = packed;
}

// --------- single-block exclusive scan of bucket totals -> bbase ----------
__global__ __launch_bounds__(1024) void k_bscan(
    const int* __restrict__ scur, int* __restrict__ bbase) {
  __shared__ int warp_sums[16];
  __shared__ int s_running;
  int t = threadIdx.x;
  int lane = t & 63, w = t >> 6;
  if (t == 0) s_running = 0;
  __syncthreads();
  for (int base = 0; base < NB; base += 1024) {
    int i = base + t;
    int v = 0;
    if (i < NB) {
#pragma unroll
      for (int g = 0; g < SEG; ++g) v += min(scur[i * SEG + g], CAP_S);
    }
    int x = v;
#pragma unroll
    for (int o = 1; o < 64; o <<= 1) {
      int y = __shfl_up(x, o, 64);
      if (lane >= o) x += y;
    }
    if (lane == 63) warp_sums[w] = x;
    __syncthreads();
    if (w == 0) {
      int ws = (lane < 16) ? warp_sums[lane] : 0;
#pragma unroll
      for (int o = 1; o < 16; o <<= 1) {
        int y = __shfl_up(ws, o, 64);
        if (lane >= o) ws += y;
      }
      if (lane < 16) warp_sums[lane] = ws;
    }
    __syncthreads();
    int incl = x + (w > 0 ? warp_sums[w - 1] : 0);
    int excl = s_running + incl - v;
    if (i < NB) bbase[i] = excl;
    __syncthreads();
    if (t == 1023) s_running += incl;
    __syncthreads();
  }
}

// ------ block per bucket: LDS degree count + prefix, coalesced CSR fill ---
__global__ __launch_bounds__(256) void k_bfill(
    const unsigned* __restrict__ buf, const int* __restrict__ scur,
    const int* __restrict__ bbase, int* __restrict__ deg,
    int* __restrict__ offs, int* __restrict__ eidx) {
  __shared__ int ncnt[NPB];
  __shared__ int ncur[NPB];
  __shared__ int segn[SEG];
  int b = blockIdx.x, t = threadIdx.x;
  if (t < NPB) ncnt[t] = 0;
  if (t < SEG) segn[t] = min(scur[b * SEG + t], CAP_S);
  __syncthreads();
  const unsigned* bb = buf + (size_t)b * SEG * CAP_S;
  for (int slot = t; slot < SEG * CAP_S; slot += 256) {
    int g = slot / CAP_S, j = slot % CAP_S;
    if (j < segn[g]) atomicAdd(&ncnt[bb[slot] >> 17], 1);
  }
  __syncthreads();
  if (t < 64) {                       // wave 0: 32-wide exclusive scan
    int lane = t;
    int c = (lane < NPB) ? ncnt[lane] : 0;
    int x = c;
#pragma unroll
    for (int o = 1; o < 32; o <<= 1) {
      int y = __shfl_up(x, o, 64);
      if (lane >= o) x += y;
    }
    if (lane < NPB) {
      int excl = x - c;
      ncur[lane] = excl;
      int gn = b * NPB + lane;
      deg[gn] = c;
      offs[gn] = bbase[b] + excl;
    }
  }
  __syncthreads();
  int base = bbase[b];
  for (int slot = t; slot < SEG * CAP_S; slot += 256) {
    int g = slot / CAP_S, j = slot % CAP_S;
    if (j < segn[g]) {
      unsigned w = bb[slot];
      int p = atomicAdd(&ncur[w >> 17], 1);
      eidx[base + p] = (int)(w & 0x1FFFF);   // dense ~2KB region: ~1x write amp
    }
  }
}

// ---- Gather layer 1: hp = dropout(lrelu(mean(xl[nbrs]) + b1 + xr)) ------
// (round-4 proven) One wave per node, half-wave per edge; broadcast index
// loads, 4 independent row loads in flight; shfl only after reconvergence.
__global__ __launch_bounds__(256) void k_gather1(
    const float* __restrict__ xl, const float* __restrict__ xr,
    const int* __restrict__ offs, const int* __restrict__ deg,
    const int* __restrict__ eidx, const float* __restrict__ b1,
    float* __restrict__ hp) {
  int wid = (int)((blockIdx.x * blockDim.x + threadIdx.x) >> 6);
  int lane = threadIdx.x & 63;
  if (wid >= N_NODES) return;
  int c = lane & 31, half = lane >> 5;
  int off = offs[wid];
  int dg = deg[wid];
  float acc = 0.f;
  int k = half;
  for (; k + 6 < dg; k += 8) {
    int s0 = eidx[off + k];
    int s1 = eidx[off + k + 2];
    int s2 = eidx[off + k + 4];
    int s3 = eidx[off + k + 6];
    float a0 = xl[s0 * 32 + c];
    float a1 = xl[s1 * 32 + c];
    float a2 = xl[s2 * 32 + c];
    float a3 = xl[s3 * 32 + c];
    acc += a0; acc += a1; acc += a2; acc += a3;
  }
  for (; k < dg; k += 2) {
    int s = eidx[off + k];
    acc += xl[s * 32 + c];
  }
  acc += __shfl_xor(acc, 32, 64);
  if (lane < 32) {
    float inv = 1.0f / fmaxf((float)dg, 1.0f);
    int j = wid * 32 + c;
    float v = acc * inv + b1[c] + xr[j];
    v = (v > 0.f) ? v : 0.01f * v;
    hp[j] = keep_bit(DK0.a, DK0.b, (unsigned)j) ? 2.0f * v : 0.0f;
  }
}

// ---- Gather layer 2 fused with output GEMM + dropout + L2 norm ----------
__global__ __launch_bounds__(256) void k_out(
    const float* __restrict__ hp, const int* __restrict__ offs,
    const int* __restrict__ deg, const int* __restrict__ eidx,
    const float* __restrict__ W2l, const float* __restrict__ b2,
    const float* __restrict__ W2r, float* __restrict__ out) {
  int wid = (int)((blockIdx.x * blockDim.x + threadIdx.x) >> 6);
  int lane = threadIdx.x & 63;
  if (wid >= N_NODES) return;
  int c = lane & 31, half = lane >> 5;
  int off = offs[wid];
  int dg = deg[wid];
  float acc = 0.f;
  int k = half;
  for (; k + 6 < dg; k += 8) {
    int s0 = eidx[off + k];
    int s1 = eidx[off + k + 2];
    int s2 = eidx[off + k + 4];
    int s3 = eidx[off + k + 6];
    float a0 = hp[s0 * 32 + c];
    float a1 = hp[s1 * 32 + c];
    float a2 = hp[s2 * 32 + c];
    float a3 = hp[s3 * 32 + c];
    acc += a0; acc += a1; acc += a2; acc += a3;
  }
  for (; k < dg; k += 2) {
    int s = eidx[off + k];
    acc += hp[s * 32 + c];
  }
  acc += __shfl_xor(acc, 32, 64);
  float inv = 1.0f / fmaxf((float)dg, 1.0f);
  float rv = (lane < 32) ? acc * inv : hp[wid * 32 + c];
  float s1 = 0.f, s2 = 0.f;
#pragma unroll
  for (int kk = 0; kk < 32; ++kk) {
    float a = __shfl(rv, kk, 64);
    float h = __shfl(rv, 32 + kk, 64);
    s1 += a * W2l[kk * 64 + lane];
    s2 += h * W2r[kk * 64 + lane];
  }
  float v = s1 + b2[lane] + s2;
  unsigned j = (unsigned)(wid * 64 + lane);
  float d = keep_bit(DK1.a, DK1.b, j) ? 2.0f * v : 0.0f;
  float ss = d * d;
#pragma unroll
  for (int o = 32; o > 0; o >>= 1) ss += __shfl_xor(ss, o, 64);
  float scale = 1.0f / fmaxf(sqrtf(ss), 1e-12f);
  out[j] = d * scale;
}

// --------------------------------------------------------------------------
extern "C" void kernel_launch(void* const* d_in, const int* in_sizes, int n_in,
                              void* d_out, int out_size, void* d_ws, size_t ws_size,
                              hipStream_t stream) {
  const float* x   = (const float*)d_in[0];
  const int*   ei  = (const int*)d_in[1];
  const float* W1l = (const float*)d_in[2];
  const float* b1  = (const float*)d_in[3];
  const float* W1r = (const float*)d_in[4];
  const float* W2l = (const float*)d_in[5];
  const float* b2  = (const float*)d_in[6];
  const float* W2r = (const float*)d_in[7];
  float* out = (float*)d_out;

  const int* src = ei;            // edge_index[0]
  const int* dst = ei + N_EDGES;  // edge_index[1]

  const size_t F32 = (size_t)N_NODES * 32;
  float* xl     = (float*)d_ws;                  // 12.8 MB
  float* xr     = xl + F32;                      // 12.8 MB
  float* hp     = xr + F32;                      // 12.8 MB
  int* scur     = (int*)(hp + F32);              // 100 KB
  int* bbase    = scur + NB * SEG;               // 12.5 KB
  int* deg      = bbase + NB;                    // 400 KB
  int* offs     = deg + N_NODES;                 // 400 KB
  int* eidx     = offs + N_NODES;                // 6.4 MB
  unsigned* buf = (unsigned*)(eidx + N_EDGES);   // 12.8 MB  (total ~58.6 MB)

  hipMemsetAsync(scur, 0, (size_t)NB * SEG * sizeof(int), stream);

  const int EB = (N_EDGES + 255) / 256;
  k_bin<<<EB, 256, 0, stream>>>(src, dst, scur, buf);
  k_bscan<<<1, 1024, 0, stream>>>(scur, bbase);
  k_bfill<<<NB, 256, 0, stream>>>(buf, scur, bbase, deg, offs, eidx);

  k_transform1<<<(N_NODES + 3) / 4, 256, 0, stream>>>(x, W1l, W1r, xl, xr);
  k_gather1<<<(N_NODES + 3) / 4, 256, 0, stream>>>(xl, xr, offs, deg, eidx, b1, hp);
  k_out<<<(N_NODES + 3) / 4, 256, 0, stream>>>(hp, offs, deg, eidx, W2l, b2, W2r, out);
}